// Round 1
// 126.081 us; speedup vs baseline: 1.0635x; 1.0635x over previous
//
#include <hip/hip_runtime.h>

#define N_L 8
#define BP 4   // pairs per thread
#define BT 2   // triples per thread

// ---------------------------------------------------------------------------
// Block (256 threads = 4 waves) sum reduction; result valid on thread 0.
// ---------------------------------------------------------------------------
__device__ __forceinline__ float block_reduce_sum(float v, float* smem) {
#pragma unroll
  for (int off = 32; off > 0; off >>= 1) v += __shfl_down(v, off, 64);
  int lane = threadIdx.x & 63;
  int wid  = threadIdx.x >> 6;
  if (lane == 0) smem[wid] = v;
  __syncthreads();
  if (threadIdx.x < 4) {
    v = smem[threadIdx.x];
    v += __shfl_down(v, 2, 64);
    v += __shfl_down(v, 1, 64);
  }
  return v;
}

// ---------------------------------------------------------------------------
// Row pointer resolution. Fast path: fidx == arange(nF) (sorted-unique ints
// with fidx[0]==0 and fidx[nF-1]==nF-1 implies identity), so
//   v < nF  -> fixed row v;  else -> trainable row v-nF.
// Fallback: binary search in tab (LDS-staged when nF<=1024).
// ---------------------------------------------------------------------------
__device__ __forceinline__ const float* row_ptr(
    int v, bool ar, const int* __restrict__ tab, int nF,
    const float* __restrict__ tr, const float* __restrict__ fx) {
  if (ar) {
    return (v < nF) ? (fx + (size_t)v * N_L) : (tr + (size_t)(v - nF) * N_L);
  }
  int lo = 0, hi = nF;
  while (lo < hi) {
    int mid = (lo + hi) >> 1;
    if (tab[mid] < v) lo = mid + 1; else hi = mid;
  }
  return (lo < nF && tab[lo] == v) ? (fx + (size_t)lo * N_L)
                                   : (tr + (size_t)(v - lo) * N_L);
}

// Softmax over 8 in-register values; identical op order to the previous
// materialize_P kernel (max, expf, ordered sum, reciprocal, scale).
__device__ __forceinline__ void softmax8(float p[N_L]) {
  float m = p[0];
#pragma unroll
  for (int i = 1; i < N_L; ++i) m = fmaxf(m, p[i]);
  float s = 0.f;
#pragma unroll
  for (int i = 0; i < N_L; ++i) { p[i] = __expf(p[i] - m); s += p[i]; }
  float r = 1.0f / s;
#pragma unroll
  for (int i = 0; i < N_L; ++i) p[i] *= r;
}

// ---------------------------------------------------------------------------
// Single fused kernel: thread-per-simplex with G-way batching. All index
// loads issue first (non-temporal: the 11.2MB index stream must not evict
// the 3.2MB row table from L2), then ALL row loads (independent, one
// waitcnt group), then softmax+dot in registers. Tails branch-free.
// Pair term:   -(p.q)                        [+2/pair in cst]
// Triple term: -4*(d01+d02+d12) + (16/3)*T   [+8/tri in cst]
// Finalize fused via done-counter. acc/cnt zeroed by hipMemsetAsync.
// ---------------------------------------------------------------------------
__global__ __launch_bounds__(256) void fused_energy(
    const float* __restrict__ tr, const float* __restrict__ fx,
    const int* __restrict__ fidx, int nF,
    const int* __restrict__ s1, int nP,
    const int* __restrict__ s2, int nT,
    double* __restrict__ acc, unsigned int* __restrict__ cnt,
    int pairBlocks, int totalBlocks,
    float* __restrict__ out, double cst) {
  __shared__ float smem[4];
  __shared__ int sf[1024];

  const bool ar = (nF == 0) || (fidx[0] == 0 && fidx[nF - 1] == nF - 1);
  const bool useLds = (!ar && nF <= 1024);
  if (useLds) {
    for (int j = threadIdx.x; j < nF; j += 256) sf[j] = fidx[j];
    __syncthreads();
  }
  const int* __restrict__ tab = useLds ? sf : fidx;

  float local = 0.f;

  if ((int)blockIdx.x < pairBlocks) {
    const unsigned long long* __restrict__ s1q = (const unsigned long long*)s1;
    int base = blockIdx.x * (256 * BP) + threadIdx.x;
    int   va[BP], vb[BP];
    float w[BP];
#pragma unroll
    for (int u = 0; u < BP; ++u) {
      int i  = base + u * 256;
      int ii = min(i, nP - 1);
      w[u]   = (i < nP) ? 1.0f : 0.0f;
      unsigned long long q = __builtin_nontemporal_load(s1q + ii);
      va[u] = (int)(unsigned int)q;
      vb[u] = (int)(q >> 32);
    }
    float4 a0[BP], a1[BP], b0[BP], b1[BP];
#pragma unroll
    for (int u = 0; u < BP; ++u) {
      const float4* A = (const float4*)row_ptr(va[u], ar, tab, nF, tr, fx);
      const float4* B = (const float4*)row_ptr(vb[u], ar, tab, nF, tr, fx);
      a0[u] = A[0]; a1[u] = A[1];
      b0[u] = B[0]; b1[u] = B[1];
    }
#pragma unroll
    for (int u = 0; u < BP; ++u) {
      float pa[8] = {a0[u].x, a0[u].y, a0[u].z, a0[u].w, a1[u].x, a1[u].y, a1[u].z, a1[u].w};
      float pb[8] = {b0[u].x, b0[u].y, b0[u].z, b0[u].w, b1[u].x, b1[u].y, b1[u].z, b1[u].w};
      softmax8(pa);
      softmax8(pb);
      float d = 0.f;
#pragma unroll
      for (int t = 0; t < N_L; ++t) d += pa[t] * pb[t];
      local -= w[u] * d;
    }
  } else {
    int base = (blockIdx.x - pairBlocks) * (256 * BT) + threadIdx.x;
    int   v0[BT], v1[BT], v2[BT];
    float w[BT];
#pragma unroll
    for (int u = 0; u < BT; ++u) {
      int i  = base + u * 256;
      int ii = min(i, nT - 1);
      w[u]   = (i < nT) ? 1.0f : 0.0f;
      v0[u] = __builtin_nontemporal_load(s2 + 3 * ii + 0);
      v1[u] = __builtin_nontemporal_load(s2 + 3 * ii + 1);
      v2[u] = __builtin_nontemporal_load(s2 + 3 * ii + 2);
    }
    float4 a0[BT], a1[BT], b0[BT], b1[BT], c0[BT], c1[BT];
#pragma unroll
    for (int u = 0; u < BT; ++u) {
      const float4* A = (const float4*)row_ptr(v0[u], ar, tab, nF, tr, fx);
      const float4* B = (const float4*)row_ptr(v1[u], ar, tab, nF, tr, fx);
      const float4* C = (const float4*)row_ptr(v2[u], ar, tab, nF, tr, fx);
      a0[u] = A[0]; a1[u] = A[1];
      b0[u] = B[0]; b1[u] = B[1];
      c0[u] = C[0]; c1[u] = C[1];
    }
#pragma unroll
    for (int u = 0; u < BT; ++u) {
      float pa[8] = {a0[u].x, a0[u].y, a0[u].z, a0[u].w, a1[u].x, a1[u].y, a1[u].z, a1[u].w};
      float pb[8] = {b0[u].x, b0[u].y, b0[u].z, b0[u].w, b1[u].x, b1[u].y, b1[u].z, b1[u].w};
      float pc[8] = {c0[u].x, c0[u].y, c0[u].z, c0[u].w, c1[u].x, c1[u].y, c1[u].z, c1[u].w};
      softmax8(pa);
      softmax8(pb);
      softmax8(pc);
      float d01 = 0.f, d02 = 0.f, d12 = 0.f, t3 = 0.f;
#pragma unroll
      for (int t = 0; t < N_L; ++t) {
        d01 += pa[t] * pb[t];
        d02 += pa[t] * pc[t];
        d12 += pb[t] * pc[t];
        t3  += pa[t] * pb[t] * pc[t];
      }
      local += w[u] * (-4.0f * (d01 + d02 + d12) + (16.0f / 3.0f) * t3);
    }
  }

  float bsum = block_reduce_sum(local, smem);
  if (threadIdx.x == 0) {
    atomicAdd(acc, (double)bsum);
    __threadfence();
    unsigned int done = atomicAdd(cnt, 1u);
    if (done == (unsigned int)(totalBlocks - 1)) {
      double total = atomicAdd(acc, 0.0);  // coherent read
      out[0] = (float)(cst + total);
    }
  }
}

extern "C" void kernel_launch(void* const* d_in, const int* in_sizes, int n_in,
                              void* d_out, int out_size, void* d_ws, size_t ws_size,
                              hipStream_t stream) {
  const float* tr   = (const float*)d_in[0];  // (N_V-N_FIXED, 8) f32
  const float* fx   = (const float*)d_in[1];  // (N_FIXED, 8) f32
  const int*   fidx = (const int*)d_in[2];    // (N_FIXED,) i32 (sorted)
  const int*   s1   = (const int*)d_in[3];    // (nP, 2) i32
  const int*   s2   = (const int*)d_in[4];    // (nT, 3) i32

  int nF = in_sizes[2];
  int nP = in_sizes[3] / 2;
  int nT = in_sizes[4] / 3;

  double*       acc = (double*)d_ws;                      // @0, 8B
  unsigned int* cnt = (unsigned int*)((char*)d_ws + 16);  // @16, 4B
  float*        out = (float*)d_out;

  double cst = 2.0 * (double)nP + 8.0 * (double)nT;

  // zero acc + done-counter (graph-capturable)
  hipMemsetAsync(d_ws, 0, 32, stream);

  int pairBlocks  = (nP + 256 * BP - 1) / (256 * BP);
  int triBlocks   = (nT + 256 * BT - 1) / (256 * BT);
  int totalBlocks = pairBlocks + triBlocks;

  fused_energy<<<totalBlocks, 256, 0, stream>>>(
      tr, fx, fidx, nF, s1, nP, s2, nT, acc, cnt,
      pairBlocks, totalBlocks, out, cst);
}

// Round 2
// 122.056 us; speedup vs baseline: 1.0986x; 1.0330x over previous
//
#include <hip/hip_runtime.h>
#include <hip/hip_fp16.h>

#define N_L 8
#define BP 4   // pairs per thread
#define BT 2   // triples per thread

// ---------------------------------------------------------------------------
// Block (256 threads = 4 waves) sum reduction; result valid on thread 0.
// ---------------------------------------------------------------------------
__device__ __forceinline__ float block_reduce_sum(float v, float* smem) {
#pragma unroll
  for (int off = 32; off > 0; off >>= 1) v += __shfl_down(v, off, 64);
  int lane = threadIdx.x & 63;
  int wid  = threadIdx.x >> 6;
  if (lane == 0) smem[wid] = v;
  __syncthreads();
  if (threadIdx.x < 4) {
    v = smem[threadIdx.x];
    v += __shfl_down(v, 2, 64);
    v += __shfl_down(v, 1, 64);
  }
  return v;
}

// ---------------------------------------------------------------------------
// Materialize fp16 softmax table: nV x 8 half = 16B rows (ONE dwordx4 per
// random row-gather in the hot kernel instead of two). Softmax in f32,
// round-to-nearest fp16 at store. Also zero-inits acc + done-counter
// (replaces the hipMemsetAsync dispatch).
// Fast path: fidx == arange(nF); fallback binary search (LDS-staged).
// ---------------------------------------------------------------------------
__global__ __launch_bounds__(256) void materialize_P16(
    const float* __restrict__ tr, const float* __restrict__ fx,
    const int* __restrict__ fidx, int nF, int nV,
    int4* __restrict__ T, double* __restrict__ acc,
    unsigned int* __restrict__ cnt) {
  __shared__ int sf[1024];
  const bool ar = (nF == 0) || (fidx[0] == 0 && fidx[nF - 1] == nF - 1);
  const bool useLds = (!ar && nF <= 1024);
  if (useLds) {
    for (int j = threadIdx.x; j < nF; j += 256) sf[j] = fidx[j];
    __syncthreads();
  }
  int v = blockIdx.x * 256 + threadIdx.x;
  if (v == 0) { acc[0] = 0.0; cnt[0] = 0u; }
  if (v >= nV) return;

  const float* src;
  if (ar) {
    src = (v < nF) ? (fx + (size_t)v * N_L) : (tr + (size_t)(v - nF) * N_L);
  } else {
    const int* __restrict__ tab = useLds ? sf : fidx;
    int lo = 0, hi = nF;
    while (lo < hi) {
      int mid = (lo + hi) >> 1;
      if (tab[mid] < v) lo = mid + 1; else hi = mid;
    }
    src = (lo < nF && tab[lo] == v) ? (fx + (size_t)lo * N_L)
                                    : (tr + (size_t)(v - lo) * N_L);
  }
  float p[N_L];
  float4 a = *(const float4*)src;
  float4 b = *(const float4*)(src + 4);
  p[0] = a.x; p[1] = a.y; p[2] = a.z; p[3] = a.w;
  p[4] = b.x; p[5] = b.y; p[6] = b.z; p[7] = b.w;
  float m = p[0];
#pragma unroll
  for (int i = 1; i < N_L; ++i) m = fmaxf(m, p[i]);
  float s = 0.f;
#pragma unroll
  for (int i = 0; i < N_L; ++i) { p[i] = __expf(p[i] - m); s += p[i]; }
  float r = 1.0f / s;
  __half2 h0 = __floats2half2_rn(p[0] * r, p[1] * r);
  __half2 h1 = __floats2half2_rn(p[2] * r, p[3] * r);
  __half2 h2 = __floats2half2_rn(p[4] * r, p[5] * r);
  __half2 h3 = __floats2half2_rn(p[6] * r, p[7] * r);
  int4 o;
  o.x = *(const int*)&h0;
  o.y = *(const int*)&h1;
  o.z = *(const int*)&h2;
  o.w = *(const int*)&h3;
  T[v] = o;
}

__device__ __forceinline__ void unpack8(int4 q, float p[N_L]) {
  float2 f;
  f = __half22float2(*(const __half2*)&q.x); p[0] = f.x; p[1] = f.y;
  f = __half22float2(*(const __half2*)&q.y); p[2] = f.x; p[3] = f.y;
  f = __half22float2(*(const __half2*)&q.z); p[4] = f.x; p[5] = f.y;
  f = __half22float2(*(const __half2*)&q.w); p[6] = f.x; p[7] = f.y;
}

// ---------------------------------------------------------------------------
// Gather over the 16B-row fp16 table. Same block geometry as round 1
// (BP=4/BT=2, 1564 blocks) — only the per-row request count changes (2->1).
// Index loads non-temporal (the 11.2MB stream must not evict the 1.6MB
// table from L2). Tails branch-free. Finalize fused via done-counter.
// ---------------------------------------------------------------------------
__global__ __launch_bounds__(256) void gather_energy16(
    const int4* __restrict__ T,
    const int* __restrict__ s1, int nP,
    const int* __restrict__ s2, int nT,
    double* __restrict__ acc, unsigned int* __restrict__ cnt,
    int pairBlocks, int totalBlocks,
    float* __restrict__ out, double cst) {
  __shared__ float smem[4];
  float local = 0.f;

  if ((int)blockIdx.x < pairBlocks) {
    const unsigned long long* __restrict__ s1q = (const unsigned long long*)s1;
    int base = blockIdx.x * (256 * BP) + threadIdx.x;
    int   va[BP], vb[BP];
    float w[BP];
#pragma unroll
    for (int u = 0; u < BP; ++u) {
      int i  = base + u * 256;
      int ii = min(i, nP - 1);
      w[u]   = (i < nP) ? 1.0f : 0.0f;
      unsigned long long q = __builtin_nontemporal_load(s1q + ii);
      va[u] = (int)(unsigned int)q;
      vb[u] = (int)(q >> 32);
    }
    int4 qa[BP], qb[BP];
#pragma unroll
    for (int u = 0; u < BP; ++u) {
      qa[u] = T[va[u]];
      qb[u] = T[vb[u]];
    }
#pragma unroll
    for (int u = 0; u < BP; ++u) {
      float pa[N_L], pb[N_L];
      unpack8(qa[u], pa);
      unpack8(qb[u], pb);
      float d = 0.f;
#pragma unroll
      for (int t = 0; t < N_L; ++t) d += pa[t] * pb[t];
      local -= w[u] * d;
    }
  } else {
    int base = (blockIdx.x - pairBlocks) * (256 * BT) + threadIdx.x;
    int   v0[BT], v1[BT], v2[BT];
    float w[BT];
#pragma unroll
    for (int u = 0; u < BT; ++u) {
      int i  = base + u * 256;
      int ii = min(i, nT - 1);
      w[u]   = (i < nT) ? 1.0f : 0.0f;
      v0[u] = __builtin_nontemporal_load(s2 + 3 * ii + 0);
      v1[u] = __builtin_nontemporal_load(s2 + 3 * ii + 1);
      v2[u] = __builtin_nontemporal_load(s2 + 3 * ii + 2);
    }
    int4 qa[BT], qb[BT], qc[BT];
#pragma unroll
    for (int u = 0; u < BT; ++u) {
      qa[u] = T[v0[u]];
      qb[u] = T[v1[u]];
      qc[u] = T[v2[u]];
    }
#pragma unroll
    for (int u = 0; u < BT; ++u) {
      float pa[N_L], pb[N_L], pc[N_L];
      unpack8(qa[u], pa);
      unpack8(qb[u], pb);
      unpack8(qc[u], pc);
      float d01 = 0.f, d02 = 0.f, d12 = 0.f, t3 = 0.f;
#pragma unroll
      for (int t = 0; t < N_L; ++t) {
        d01 += pa[t] * pb[t];
        d02 += pa[t] * pc[t];
        d12 += pb[t] * pc[t];
        t3  += pa[t] * pb[t] * pc[t];
      }
      local += w[u] * (-4.0f * (d01 + d02 + d12) + (16.0f / 3.0f) * t3);
    }
  }

  float bsum = block_reduce_sum(local, smem);
  if (threadIdx.x == 0) {
    atomicAdd(acc, (double)bsum);
    __threadfence();
    unsigned int done = atomicAdd(cnt, 1u);
    if (done == (unsigned int)(totalBlocks - 1)) {
      double total = atomicAdd(acc, 0.0);  // coherent read
      out[0] = (float)(cst + total);
    }
  }
}

// ---------------------------------------------------------------------------
// ws-too-small fallback: round-1 fully-fused f32 kernel (proven).
// ---------------------------------------------------------------------------
__device__ __forceinline__ const float* row_ptr(
    int v, bool ar, const int* __restrict__ tab, int nF,
    const float* __restrict__ tr, const float* __restrict__ fx) {
  if (ar) {
    return (v < nF) ? (fx + (size_t)v * N_L) : (tr + (size_t)(v - nF) * N_L);
  }
  int lo = 0, hi = nF;
  while (lo < hi) {
    int mid = (lo + hi) >> 1;
    if (tab[mid] < v) lo = mid + 1; else hi = mid;
  }
  return (lo < nF && tab[lo] == v) ? (fx + (size_t)lo * N_L)
                                   : (tr + (size_t)(v - lo) * N_L);
}

__device__ __forceinline__ void softmax8(float p[N_L]) {
  float m = p[0];
#pragma unroll
  for (int i = 1; i < N_L; ++i) m = fmaxf(m, p[i]);
  float s = 0.f;
#pragma unroll
  for (int i = 0; i < N_L; ++i) { p[i] = __expf(p[i] - m); s += p[i]; }
  float r = 1.0f / s;
#pragma unroll
  for (int i = 0; i < N_L; ++i) p[i] *= r;
}

__global__ __launch_bounds__(256) void fused_energy(
    const float* __restrict__ tr, const float* __restrict__ fx,
    const int* __restrict__ fidx, int nF,
    const int* __restrict__ s1, int nP,
    const int* __restrict__ s2, int nT,
    double* __restrict__ acc, unsigned int* __restrict__ cnt,
    int pairBlocks, int totalBlocks,
    float* __restrict__ out, double cst) {
  __shared__ float smem[4];
  __shared__ int sf[1024];

  const bool ar = (nF == 0) || (fidx[0] == 0 && fidx[nF - 1] == nF - 1);
  const bool useLds = (!ar && nF <= 1024);
  if (useLds) {
    for (int j = threadIdx.x; j < nF; j += 256) sf[j] = fidx[j];
    __syncthreads();
  }
  const int* __restrict__ tab = useLds ? sf : fidx;

  float local = 0.f;

  if ((int)blockIdx.x < pairBlocks) {
    const unsigned long long* __restrict__ s1q = (const unsigned long long*)s1;
    int base = blockIdx.x * (256 * BP) + threadIdx.x;
    int   va[BP], vb[BP];
    float w[BP];
#pragma unroll
    for (int u = 0; u < BP; ++u) {
      int i  = base + u * 256;
      int ii = min(i, nP - 1);
      w[u]   = (i < nP) ? 1.0f : 0.0f;
      unsigned long long q = __builtin_nontemporal_load(s1q + ii);
      va[u] = (int)(unsigned int)q;
      vb[u] = (int)(q >> 32);
    }
    float4 a0[BP], a1[BP], b0[BP], b1[BP];
#pragma unroll
    for (int u = 0; u < BP; ++u) {
      const float4* A = (const float4*)row_ptr(va[u], ar, tab, nF, tr, fx);
      const float4* B = (const float4*)row_ptr(vb[u], ar, tab, nF, tr, fx);
      a0[u] = A[0]; a1[u] = A[1];
      b0[u] = B[0]; b1[u] = B[1];
    }
#pragma unroll
    for (int u = 0; u < BP; ++u) {
      float pa[8] = {a0[u].x, a0[u].y, a0[u].z, a0[u].w, a1[u].x, a1[u].y, a1[u].z, a1[u].w};
      float pb[8] = {b0[u].x, b0[u].y, b0[u].z, b0[u].w, b1[u].x, b1[u].y, b1[u].z, b1[u].w};
      softmax8(pa);
      softmax8(pb);
      float d = 0.f;
#pragma unroll
      for (int t = 0; t < N_L; ++t) d += pa[t] * pb[t];
      local -= w[u] * d;
    }
  } else {
    int base = (blockIdx.x - pairBlocks) * (256 * BT) + threadIdx.x;
    int   v0[BT], v1[BT], v2[BT];
    float w[BT];
#pragma unroll
    for (int u = 0; u < BT; ++u) {
      int i  = base + u * 256;
      int ii = min(i, nT - 1);
      w[u]   = (i < nT) ? 1.0f : 0.0f;
      v0[u] = __builtin_nontemporal_load(s2 + 3 * ii + 0);
      v1[u] = __builtin_nontemporal_load(s2 + 3 * ii + 1);
      v2[u] = __builtin_nontemporal_load(s2 + 3 * ii + 2);
    }
    float4 a0[BT], a1[BT], b0[BT], b1[BT], c0[BT], c1[BT];
#pragma unroll
    for (int u = 0; u < BT; ++u) {
      const float4* A = (const float4*)row_ptr(v0[u], ar, tab, nF, tr, fx);
      const float4* B = (const float4*)row_ptr(v1[u], ar, tab, nF, tr, fx);
      const float4* C = (const float4*)row_ptr(v2[u], ar, tab, nF, tr, fx);
      a0[u] = A[0]; a1[u] = A[1];
      b0[u] = B[0]; b1[u] = B[1];
      c0[u] = C[0]; c1[u] = C[1];
    }
#pragma unroll
    for (int u = 0; u < BT; ++u) {
      float pa[8] = {a0[u].x, a0[u].y, a0[u].z, a0[u].w, a1[u].x, a1[u].y, a1[u].z, a1[u].w};
      float pb[8] = {b0[u].x, b0[u].y, b0[u].z, b0[u].w, b1[u].x, b1[u].y, b1[u].z, b1[u].w};
      float pc[8] = {c0[u].x, c0[u].y, c0[u].z, c0[u].w, c1[u].x, c1[u].y, c1[u].z, c1[u].w};
      softmax8(pa);
      softmax8(pb);
      softmax8(pc);
      float d01 = 0.f, d02 = 0.f, d12 = 0.f, t3 = 0.f;
#pragma unroll
      for (int t = 0; t < N_L; ++t) {
        d01 += pa[t] * pb[t];
        d02 += pa[t] * pc[t];
        d12 += pb[t] * pc[t];
        t3  += pa[t] * pb[t] * pc[t];
      }
      local += w[u] * (-4.0f * (d01 + d02 + d12) + (16.0f / 3.0f) * t3);
    }
  }

  float bsum = block_reduce_sum(local, smem);
  if (threadIdx.x == 0) {
    atomicAdd(acc, (double)bsum);
    __threadfence();
    unsigned int done = atomicAdd(cnt, 1u);
    if (done == (unsigned int)(totalBlocks - 1)) {
      double total = atomicAdd(acc, 0.0);  // coherent read
      out[0] = (float)(cst + total);
    }
  }
}

extern "C" void kernel_launch(void* const* d_in, const int* in_sizes, int n_in,
                              void* d_out, int out_size, void* d_ws, size_t ws_size,
                              hipStream_t stream) {
  const float* tr   = (const float*)d_in[0];  // (N_V-N_FIXED, 8) f32
  const float* fx   = (const float*)d_in[1];  // (N_FIXED, 8) f32
  const int*   fidx = (const int*)d_in[2];    // (N_FIXED,) i32 (sorted)
  const int*   s1   = (const int*)d_in[3];    // (nP, 2) i32
  const int*   s2   = (const int*)d_in[4];    // (nT, 3) i32

  int nF = in_sizes[2];
  int nP = in_sizes[3] / 2;
  int nT = in_sizes[4] / 3;
  int nV = (in_sizes[0] + in_sizes[1]) / N_L;

  double*       acc = (double*)d_ws;                      // @0, 8B
  unsigned int* cnt = (unsigned int*)((char*)d_ws + 16);  // @16, 4B
  int4*         T   = (int4*)((char*)d_ws + 256);         // nV x 16B fp16 rows
  float*        out = (float*)d_out;

  double cst = 2.0 * (double)nP + 8.0 * (double)nT;

  int pairBlocks  = (nP + 256 * BP - 1) / (256 * BP);
  int triBlocks   = (nT + 256 * BT - 1) / (256 * BT);
  int totalBlocks = pairBlocks + triBlocks;

  size_t need = 256 + (size_t)nV * sizeof(int4);

  if (ws_size >= need) {
    materialize_P16<<<(nV + 255) / 256, 256, 0, stream>>>(tr, fx, fidx, nF, nV, T, acc, cnt);
    gather_energy16<<<totalBlocks, 256, 0, stream>>>(
        T, s1, nP, s2, nT, acc, cnt, pairBlocks, totalBlocks, out, cst);
  } else {
    hipMemsetAsync(d_ws, 0, 32, stream);
    fused_energy<<<totalBlocks, 256, 0, stream>>>(
        tr, fx, fidx, nF, s1, nP, s2, nT, acc, cnt,
        pairBlocks, totalBlocks, out, cst);
  }
}